// Round 2
// baseline (291.072 us; speedup 1.0000x reference)
//
#include <hip/hip_runtime.h>
#include <math.h>

#define DX 192
#define DY 192
#define DZ 128
#define DB 4
#define DXY (DX*DY)          // 36864
#define XG 24                // x-groups of 8 per row
#define ZC 4                 // z-chunk depth per thread
#define NCK (DZ/ZC)          // 32 chunks
#define NBLK (DB*NCK*DY*XG/256)   // 2304 blocks, exactly 9/CU

// ws layout (doubles): [0..12] sum(di*dt), [13..25] sum(dt*dt), [26] bce sum

struct Acc { float s[13]; float r[13]; float bce; };

__device__ inline void load9(float (&a)[9], const float* __restrict__ p, int xe) {
    float4 u = *(const float4*)(p);
    float4 v = *(const float4*)(p + 4);
    a[0]=u.x; a[1]=u.y; a[2]=u.z; a[3]=u.w;
    a[4]=v.x; a[5]=v.y; a[6]=v.z; a[7]=v.w;
    a[8] = p[xe];
}

// corners (z,y,x): c0=(0,0,0) c1=(0,0,1) c2=(0,1,0) c3=(0,1,1)
//                  c4=(1,0,0) c5=(1,0,1) c6=(1,1,0) c7=(1,1,1)
// Single-axis offsets (s0,s1,s2) are auto-zeroed at boundaries by the
// clamped loads (oz/oy=0 dupes the row; xe=7 dupes the edge elem), so they
// carry NO mask. Diagonals need masks only when exactly one axis clamps.
template<bool INTERIOR>
__device__ inline void compute8(const float (&Ia)[9], const float (&Ib)[9],
                                const float (&Ja)[9], const float (&Jb)[9],
                                const float (&Ta)[9], const float (&Tb)[9],
                                const float (&Ua)[9], const float (&Ub)[9],
                                float fz, float fy, float fx7, Acc& A)
{
    #pragma unroll
    for (int e = 0; e < 8; ++e) {
        const float fx = (e < 7) ? 1.0f : fx7;
        float mzy, myx, mzx, mzyx;
        if (INTERIOR) { mzy = 1.0f; myx = fx; mzx = fx; mzyx = fx; }
        else { mzy = fz*fy; myx = fy*fx; mzx = fz*fx; mzyx = mzy*fx; }
        const float c0=Ia[e], c1=Ia[e+1], c2=Ib[e], c3=Ib[e+1];
        const float c4=Ja[e], c5=Ja[e+1], c6=Jb[e], c7=Jb[e+1];
        const float d0=Ta[e], d1=Ta[e+1], d2=Tb[e], d3=Tb[e+1];
        const float d4=Ua[e], d5=Ua[e+1], d6=Ub[e], d7=Ub[e+1];
        float di, dt, dtm;
        di=c4-c0; dt=d4-d0;              A.s[0] +=di*dt;  A.r[0] +=dt*dt;   // (1,0,0)
        di=c2-c0; dt=d2-d0;              A.s[1] +=di*dt;  A.r[1] +=dt*dt;   // (0,1,0)
        di=c1-c0; dt=d1-d0;              A.s[2] +=di*dt;  A.r[2] +=dt*dt;   // (0,0,1)
        di=c6-c0; dt=d6-d0; dtm=mzy*dt;  A.s[3] +=di*dtm; A.r[3] +=dt*dtm;  // (1,1,0)
        di=c4-c2; dt=d4-d2; dtm=mzy*dt;  A.s[4] +=di*dtm; A.r[4] +=dt*dtm;  // (1,-1,0)
        di=c3-c0; dt=d3-d0; dtm=myx*dt;  A.s[5] +=di*dtm; A.r[5] +=dt*dtm;  // (0,1,1)
        di=c2-c1; dt=d2-d1; dtm=myx*dt;  A.s[6] +=di*dtm; A.r[6] +=dt*dtm;  // (0,1,-1)
        di=c4-c1; dt=d4-d1; dtm=mzx*dt;  A.s[7] +=di*dtm; A.r[7] +=dt*dtm;  // (1,0,-1)
        di=c5-c0; dt=d5-d0; dtm=mzx*dt;  A.s[8] +=di*dtm; A.r[8] +=dt*dtm;  // (1,0,1)
        di=c4-c3; dt=d4-d3; dtm=mzyx*dt; A.s[9] +=di*dtm; A.r[9] +=dt*dtm;  // (1,-1,-1)
        di=c6-c1; dt=d6-d1; dtm=mzyx*dt; A.s[10]+=di*dtm; A.r[10]+=dt*dtm;  // (1,1,-1)
        di=c7-c0; dt=d7-d0; dtm=mzyx*dt; A.s[11]+=di*dtm; A.r[11]+=dt*dtm;  // (1,1,1)
        di=c5-c2; dt=d5-d2; dtm=mzyx*dt; A.s[12]+=di*dtm; A.r[12]+=dt*dtm;  // (1,-1,1)
        float l0 = __logf(c0), l1 = __logf(1.0f - c0);
        A.bce += l1 + d0 * (l0 - l1);
    }
}

template<bool INTERIOR>
__device__ inline void zloop(const float* __restrict__ ip, const float* __restrict__ tp,
                             int oy, int xe, float fy, float fx7, int z0, Acc& A)
{
    float Ia[9], Ib[9], Ta[9], Tb[9];
    float Ja[9], Jb[9], Ua[9], Ub[9];
    load9(Ia, ip, xe); load9(Ib, ip + oy, xe);
    load9(Ta, tp, xe); load9(Tb, tp + oy, xe);
    #pragma unroll 1
    for (int k = 0; k < ZC/2; ++k) {
        int z = z0 + 2*k;
        {   // even step: current = I/T @ z, next -> J/U @ z+1
            int   oz = (INTERIOR || z < DZ-1) ? DXY : 0;
            float fz = (INTERIOR || z < DZ-1) ? 1.0f : 0.0f;
            load9(Ja, ip + oz, xe); load9(Jb, ip + oz + oy, xe);
            load9(Ua, tp + oz, xe); load9(Ub, tp + oz + oy, xe);
            compute8<INTERIOR>(Ia, Ib, Ja, Jb, Ta, Tb, Ua, Ub, fz, fy, fx7, A);
            ip += DXY; tp += DXY;
        }
        {   // odd step: current = J/U @ z+1, next -> I/T @ z+2
            int z1 = z + 1;
            int   oz = (INTERIOR || z1 < DZ-1) ? DXY : 0;
            float fz = (INTERIOR || z1 < DZ-1) ? 1.0f : 0.0f;
            load9(Ia, ip + oz, xe); load9(Ib, ip + oz + oy, xe);
            load9(Ta, tp + oz, xe); load9(Tb, tp + oz + oy, xe);
            compute8<INTERIOR>(Ja, Jb, Ia, Ib, Ua, Ub, Ta, Tb, fz, fy, fx7, A);
            ip += DXY; tp += DXY;
        }
    }
}

__global__ __launch_bounds__(256) void gc3d_main(const float* __restrict__ inp,
                                                 const float* __restrict__ tgt,
                                                 double* __restrict__ acc)
{
    int gid = blockIdx.x * 256 + threadIdx.x;
    int xg = gid % XG;
    int t1 = gid / XG;
    int y  = t1 % DY;
    int t2 = t1 / DY;
    int ck = t2 % NCK;
    int b  = t2 / NCK;
    int z0 = ck * ZC;

    long base = (((long)b * DZ + z0) * DY + y) * DX + xg * 8;
    const float* ip = inp + base;
    const float* tp = tgt + base;
    int   oy  = (y < DY-1) ? DX : 0;
    float fy  = (y < DY-1) ? 1.0f : 0.0f;
    int   xe  = (xg < XG-1) ? 8 : 7;
    float fx7 = (xg < XG-1) ? 1.0f : 0.0f;

    Acc A;
    #pragma unroll
    for (int k = 0; k < 13; ++k) { A.s[k] = 0.f; A.r[k] = 0.f; }
    A.bce = 0.f;

    // interior: fy==1 and no z in this chunk touches z==DZ-1 (wave-uniform-ish;
    // only ~2% of waves diverge — y boundary lanes and the last z-chunk)
    if ((y < DY-1) && (ck < NCK-1)) zloop<true >(ip, tp, oy, xe, fy, fx7, z0, A);
    else                            zloop<false>(ip, tp, oy, xe, fy, fx7, z0, A);

    // block reduction: wave shuffle -> LDS -> 27 double atomics per block
    float vals[27];
    #pragma unroll
    for (int k = 0; k < 13; ++k) { vals[k] = A.s[k]; vals[13+k] = A.r[k]; }
    vals[26] = A.bce;
    #pragma unroll
    for (int k = 0; k < 27; ++k) {
        #pragma unroll
        for (int o = 32; o > 0; o >>= 1) vals[k] += __shfl_down(vals[k], o, 64);
    }
    __shared__ float red[4][27];
    int lane = threadIdx.x & 63;
    int wave = threadIdx.x >> 6;
    if (lane == 0) {
        #pragma unroll
        for (int k = 0; k < 27; ++k) red[wave][k] = vals[k];
    }
    __syncthreads();
    if (threadIdx.x < 27) {
        float t = red[0][threadIdx.x] + red[1][threadIdx.x]
                + red[2][threadIdx.x] + red[3][threadIdx.x];
        atomicAdd(&acc[threadIdx.x], (double)t);
    }
}

__global__ void gc3d_final(const double* __restrict__ acc, float* __restrict__ out) {
    if (threadIdx.x == 0 && blockIdx.x == 0) {
        double s = 0.0;
        #pragma unroll
        for (int k = 0; k < 13; ++k) s += acc[k] / (acc[13 + k] + 1e-5);
        double bce = -acc[26] / (double)((long)DB * DZ * DY * DX);
        out[0] = (float)(bce + 1.0 - s / 13.0);
    }
}

extern "C" void kernel_launch(void* const* d_in, const int* in_sizes, int n_in,
                              void* d_out, int out_size, void* d_ws, size_t ws_size,
                              hipStream_t stream) {
    const float* inp = (const float*)d_in[0];
    const float* tgt = (const float*)d_in[1];
    double* acc = (double*)d_ws;

    hipMemsetAsync(d_ws, 0, 27 * sizeof(double), stream);
    gc3d_main<<<NBLK, 256, 0, stream>>>(inp, tgt, acc);
    gc3d_final<<<1, 64, 0, stream>>>(acc, (float*)d_out);
}